// Round 8
// baseline (584.228 us; speedup 1.0000x reference)
//
#include <hip/hip_runtime.h>
#include <hip/hip_bf16.h>

// Problem: B=64, L=1024, ENC=1024, DEC=1024, ATT=1024
// M = B*L = 65536, K = ENC = 1024, N = ATT = 1024
//
// Pipeline (fast path, needs ~135 MB ws), 5 dispatches:
//   ws: [featb bf16 128MB][W1T bf16 2MB][proj_h fp32 256KB][part fp32 4MB]
//   1. transpose W1 (fp32 [K][N]) -> W1T (bf16 [N][K])
//   2. proj_h = hidden@W2 + W2_b + W1_b   (combined bias)
//   3. convert features fp32 -> bf16 (featb)
//   4. GEMM proj_f = featb@W1T: 256x256 tile, BK=64, 8 waves (2Mx4N),
//      m201-style 8-phase schedule (per phase: ds_read subtile, 1 staging
//      unit, s_barrier, setprio(1), 16 MFMA, setprio(0), s_barrier),
//      counted vmcnt(8) twice per K-tile (never 0 in loop), gload_lds +
//      swizzled LDS, tanh epilogue:
//        part[nt*4 + wn][m] = sum_{a in 64-col chunk} tanh(pf+ph)*V_w
//   5. fused softmax+context: per (e-quarter, b) block redundant softmax
//      from the 16 partials (alpha in LDS; x==0 block writes alpha), then
//      context quarter from bf16 featb.

typedef __bf16 bf16x8 __attribute__((ext_vector_type(8)));
typedef float floatx4 __attribute__((ext_vector_type(4)));
typedef unsigned short ushort_t;
typedef unsigned long long u64;

__device__ __forceinline__ ushort_t f2b(float x) {
    union { float f; unsigned u; } v; v.f = x;
    unsigned r = (v.u + 0x7fffu + ((v.u >> 16) & 1u)) >> 16;  // RNE
    return (ushort_t)r;
}

__device__ __forceinline__ float b2f(ushort_t u) {
    union { unsigned u; float f; } v; v.u = (unsigned)u << 16; return v.f;
}

__device__ __forceinline__ u64 pack4(float4 f) {
    return (u64)f2b(f.x) | ((u64)f2b(f.y) << 16) |
           ((u64)f2b(f.z) << 32) | ((u64)f2b(f.w) << 48);
}

__device__ __forceinline__ void gload_lds16(const void* g, void* l) {
    __builtin_amdgcn_global_load_lds(
        (const __attribute__((address_space(1))) void*)g,
        (__attribute__((address_space(3))) void*)l, 16, 0, 0);
}

// tanh via v_exp_f32 + v_rcp_f32 (fallback kernel only)
__device__ __forceinline__ float fast_tanh(float x) {
    const float ax = fabsf(x);
    const float t  = __expf(-2.0f * ax);
    const float r  = (1.0f - t) * __builtin_amdgcn_rcpf(1.0f + t);
    return copysignf(r, x);
}

#define LOG2E2 2.885390082f   // 2/ln(2): e^{2x} = 2^{x*LOG2E2}

// ---------------- features fp32 -> bf16 -------------------------------------
__global__ __launch_bounds__(256) void convert_feat_kernel(
    const float* __restrict__ feat, ushort_t* __restrict__ featb) {
    const size_t idx = ((size_t)blockIdx.x * 256 + threadIdx.x) * 8;
    const float4 f0 = *(const float4*)(feat + idx);
    const float4 f1 = *(const float4*)(feat + idx + 4);
    *(u64*)(featb + idx)     = pack4(f0);
    *(u64*)(featb + idx + 4) = pack4(f1);
}

// ---------------- W1 transpose + bf16 convert: [K][N] fp32 -> [N][K] bf16 ---
__global__ __launch_bounds__(256) void transpose_w1_kernel(
    const float* __restrict__ w1, ushort_t* __restrict__ w1t) {
    __shared__ ushort_t tile[64][65];
    const int k0 = blockIdx.x * 64, n0 = blockIdx.y * 64;
    const int tr = threadIdx.x >> 6;   // 0..3
    const int tc = threadIdx.x & 63;   // 0..63
#pragma unroll
    for (int i = 0; i < 16; i++) {
        int r = i * 4 + tr;
        tile[tc][r] = f2b(w1[(size_t)(k0 + r) * 1024 + n0 + tc]);
    }
    __syncthreads();
#pragma unroll
    for (int i = 0; i < 16; i++) {
        int r = i * 4 + tr;
        w1t[(size_t)(n0 + r) * 1024 + k0 + tc] = tile[r][tc];
    }
}

// ---------------- proj_h = hidden @ W2 + W2_b + W1_b ------------------------
__global__ __launch_bounds__(256) void projh_kernel(
    const float* __restrict__ hidden, const float* __restrict__ w2,
    const float* __restrict__ w2b, const float* __restrict__ w1b,
    float* __restrict__ ph) {
    const int b  = blockIdx.y;
    const int al = threadIdx.x & 63;
    const int eg = threadIdx.x >> 6;            // 0..3
    const int a  = blockIdx.x * 64 + al;
    const float* h = hidden + b * 1024;
    float sum = 0.f;
    const int e0 = eg * 256;
#pragma unroll 8
    for (int e = e0; e < e0 + 256; e++)
        sum += h[e] * w2[(size_t)e * 1024 + a];
    __shared__ float red[256];
    red[threadIdx.x] = sum;
    __syncthreads();
    if (threadIdx.x < 64)
        ph[b * 1024 + a] = w2b[a] + w1b[a] + red[al] + red[al + 64] +
                           red[al + 128] + red[al + 192];
}

// ---------------- main GEMM: 256x256 tile, 8-phase schedule -----------------
// LDS per operand buffer: [2 dbuf][2 k-half][16 row-groups][1KB segment]
//   segment = 16 rows x 32 cols bf16; within a row (4 16B-blocks) block g of
//   row r is stored at slot g ^ ((r>>1)&3)  (conflict-free b128 reads,
//   SQ_LDS_BANK_CONFLICT = 0 measured on this layout).
// gload_lds dest is LINEAR (base + lane*16B); swizzle via pre-swizzled
// GLOBAL source (guide rule 21 / m173).
//
// Per K-tile: 4 phases (k-half h x m-quadrant mq); EACH phase =
//   { ds_read 4 (or 8) b128 ; issue 1 staging unit (2 gload_lds/wave) ;
//     [vmcnt(8) at phases 1,3] ; s_barrier ; setprio(1) ; 16 MFMA ;
//     setprio(0) ; s_barrier }.
// NOTE: staging ops are passed as the trailing __VA_ARGS__ of PH — a
// comma-containing macro arg in a fixed position was the R2/R3 compile
// failure (args are split before expansion).
// vmcnt ledger (steady state, per wave; gload_lds counts vmcnt):
//   at P1's vmcnt(8): outstanding = {A,B}(t,h1)+{A,B}(t+1,h0)+A(t+1,h1)+
//   B(t+1,h1) = 12 -> drains oldest 4 = {A,B}(t,h1), read in P2/P3.
//   at P3's vmcnt(8): drains {A,B}(t+1,h0), read next tile P0/P1.
//   Staging into buf d's h0 (P2) is >= 1 barrier after its last readers
//   (P0/P1 ds_reads, complete before P1's end barrier). Never vmcnt(0).

#define WAITV(n) asm volatile("s_waitcnt vmcnt(" #n ")" ::: "memory")
#define BAR() __builtin_amdgcn_s_barrier()

#define STG_A(d, h, kc) do { \
    gload_lds16(aSrc + (kc) + (h) * 32,          aDst + (d) * 16384 + (h) * 8192); \
    gload_lds16(aSrc + 131072 + (kc) + (h) * 32, aDst + (d) * 16384 + (h) * 8192 + 4096); \
  } while (0)
#define STG_B(d, h, kc) do { \
    gload_lds16(bSrc + (kc) + (h) * 32,          bDst + (d) * 16384 + (h) * 8192); \
    gload_lds16(bSrc + 131072 + (kc) + (h) * 32, bDst + (d) * 16384 + (h) * 8192 + 4096); \
  } while (0)

#define PH(d, h, mq, LB, PW, ...) do { \
    bf16x8 af[4]; \
    _Pragma("unroll") \
    for (int i_ = 0; i_ < 4; i_++) \
      af[i_] = *(const bf16x8*)(As + (d) * 16384 + (h) * 8192 + \
                                (ga + (mq) * 4 + i_) * 512 + rdo); \
    if (LB) { \
      _Pragma("unroll") \
      for (int j_ = 0; j_ < 4; j_++) \
        bf[j_] = *(const bf16x8*)(Bs + (d) * 16384 + (h) * 8192 + \
                                  (gb + j_) * 512 + rdo); \
    } \
    __VA_ARGS__; \
    PW; \
    BAR(); \
    __builtin_amdgcn_s_setprio(1); \
    _Pragma("unroll") \
    for (int i_ = 0; i_ < 4; i_++) \
      _Pragma("unroll") \
      for (int j_ = 0; j_ < 4; j_++) \
        acc[(mq) * 4 + i_][j_] = __builtin_amdgcn_mfma_f32_16x16x32_bf16( \
            af[i_], bf[j_], acc[(mq) * 4 + i_][j_], 0, 0, 0); \
    __builtin_amdgcn_s_setprio(0); \
    BAR(); \
  } while (0)

#define TILE(t, d) do { \
    const int k1_ = (((t) + 1) & 15) * 64; \
    const int k2_ = (((t) + 2) & 15) * 64; \
    PH(d, 0, 0, 1, (void)0,  STG_A((d) ^ 1, 1, k1_)); \
    PH(d, 0, 1, 0, WAITV(8), STG_B((d) ^ 1, 1, k1_)); \
    PH(d, 1, 0, 1, (void)0,  STG_A((d),     0, k2_)); \
    PH(d, 1, 1, 0, WAITV(8), STG_B((d),     0, k2_)); \
  } while (0)

__global__ __launch_bounds__(512, 2) void gemm_scores_256_kernel(
    const ushort_t* __restrict__ featb,  // [M][1024] bf16
    const ushort_t* __restrict__ w1t,    // [N][1024] bf16
    const float* __restrict__ ph,        // [B][1024] combined bias
    const float* __restrict__ vw,        // [1024]
    float* __restrict__ part) {          // [16][M] fp32 partial scores
    __shared__ ushort_t As[2 * 16384];   // 64 KB
    __shared__ ushort_t Bs[2 * 16384];   // 64 KB
    __shared__ float cbias[256];
    __shared__ float vvw[256];

    const int tid = threadIdx.x;
    // XCD-chunked bijective remap (1024 wgs % 8 == 0).
    const int orig = blockIdx.x;
    const int wgid = (orig & 7) * 128 + (orig >> 3);
    const int nt = wgid & 3;             // n fastest: 4 wgids share one A-tile
    const int mt = wgid >> 2;
    const int n0 = nt * 256;
    const int m0 = mt * 256;
    const int b  = m0 >> 10;             // one batch row per block (256|1024)

    if (tid < 256) {
        cbias[tid] = ph[(b << 10) + n0 + tid];
        vvw[tid]   = vw[n0 + tid];
    }

    const int w    = tid >> 6;           // wave 0..7: (w>>2)=M-half, (w&3)=N-quarter
    const int lane = tid & 63;
    const int q    = lane >> 4;
    const int l15  = lane & 15;
    const int rdo  = l15 * 32 + ((q ^ ((l15 >> 1) & 3)) << 3);
    const int ga   = (w >> 2) * 8;       // A row-group base for this wave
    const int gb   = (w & 3) * 4;        // B row-group base for this wave
    const int sb   = ((lane & 3) ^ ((lane >> 3) & 3)) << 3;

    const ushort_t* aSrc = featb + (size_t)(m0 + w * 16 + (lane >> 2)) * 1024 + sb;
    const ushort_t* bSrc = w1t  + (size_t)(n0 + w * 16 + (lane >> 2)) * 1024 + sb;
    ushort_t* aDst = As + w * 512;       // wave-uniform LDS base per issue
    ushort_t* bDst = Bs + w * 512;

    floatx4 acc[8][4] = {};
    bf16x8 bf[4];

    // Prologue: 12 gloads = (0,h0) (0,h1) (1,h0); wait oldest 4 = (0,h0).
    // (Waves 0-3 carry 2 extra older loads (cbias/vvw): in-order completion
    // keeps every later counted wait covering the right units.)
    STG_A(0, 0, 0);  STG_B(0, 0, 0);
    STG_A(0, 1, 0);  STG_B(0, 1, 0);
    STG_A(1, 0, 64); STG_B(1, 0, 64);
    WAITV(8); BAR();

    for (int it = 0; it < 8; it++) {
        TILE(2 * it,     0);
        TILE(2 * it + 1, 1);
    }
    WAITV(0);  // drain tail prefetches before block retires

    // Epilogue: C/D layout col=lane&15, row=q*4+reg (measured m89/m91).
    float vv[4], cbk[4];
    float sum_vvw = 0.f;
#pragma unroll
    for (int j = 0; j < 4; j++) {
        const int col = (w & 3) * 64 + j * 16 + l15;
        vv[j]  = vvw[col];
        cbk[j] = LOG2E2 * cbias[col];
        sum_vvw += vv[j];
    }
    const int slot  = nt * 4 + (w & 3);  // 16 col-chunk slots of 64
    const int rbase = m0 + (w >> 2) * 128;
#pragma unroll
    for (int mf = 0; mf < 8; mf++) {
#pragma unroll
        for (int r = 0; r < 4; r++) {
            const int row = rbase + mf * 16 + q * 4 + r;
            float s2 = 0.f;
#pragma unroll
            for (int j = 0; j < 4; j++) {
                const float arg = fmaf(LOG2E2, acc[mf][j][r], cbk[j]);
                const float e   = __builtin_amdgcn_exp2f(arg);
                s2 = fmaf(__builtin_amdgcn_rcpf(1.0f + e), vv[j], s2);
            }
            float s = fmaf(-2.0f, s2, sum_vvw);
            s += __shfl_xor(s, 1);
            s += __shfl_xor(s, 2);
            s += __shfl_xor(s, 4);
            s += __shfl_xor(s, 8);
            if (l15 == 0) part[slot * 65536 + row] = s;
        }
    }
}

// ---------------- fused softmax + context (fast path) -----------------------
// grid (4, 64), 1024 threads. Each block redundantly computes batch b's
// softmax from the 16 partials (64 KB slice, L2-resident; plain LDS trees),
// keeps alpha in LDS (block x==0 writes it out), then computes its 256-col
// context quarter from bf16 featb.
__global__ __launch_bounds__(1024) void softmax_context_kernel(
    const float* __restrict__ part, const ushort_t* __restrict__ featb,
    float* __restrict__ alpha, float* __restrict__ ctx) {
    const int b   = blockIdx.y;
    const int tid = threadIdx.x;
    __shared__ float red1[1024];
    __shared__ float al_lds[1024];
    __shared__ floatx4 red4[16 * 64];

    // score for row l = tid (same nb summation order as before)
    float s = 0.f;
    const int m = b * 1024 + tid;
#pragma unroll
    for (int nb = 0; nb < 16; nb++) s += part[nb * 65536 + m];

    // block max (LDS tree; exact)
    red1[tid] = s;
    __syncthreads();
    for (int st = 512; st > 0; st >>= 1) {
        if (tid < st) red1[tid] = fmaxf(red1[tid], red1[tid + st]);
        __syncthreads();
    }
    const float mx = red1[0];
    __syncthreads();                      // all reads of red1[0] before reuse

    const float v = __expf(s - mx);
    red1[tid] = v;
    __syncthreads();
    for (int st = 512; st > 0; st >>= 1) {
        if (tid < st) red1[tid] += red1[tid + st];
        __syncthreads();
    }
    const float av = v * (1.0f / red1[0]);
    al_lds[tid] = av;
    if (blockIdx.x == 0) alpha[m] = av;
    __syncthreads();

    // context quarter: ctx[b][e..e+3] over this block's 256 cols
    const int el = tid & 63, lg = tid >> 6;
    const int e  = blockIdx.x * 256 + el * 4;
    const ushort_t* fb = featb + ((size_t)b << 20) + e;
    floatx4 acc = {};
    const int l0 = lg * 64;
#pragma unroll 4
    for (int l = l0; l < l0 + 64; l++) {
        const float a = al_lds[l];
        const ushort4 u = *(const ushort4*)(fb + (size_t)l * 1024);
        acc[0] = fmaf(a, b2f(u.x), acc[0]);
        acc[1] = fmaf(a, b2f(u.y), acc[1]);
        acc[2] = fmaf(a, b2f(u.z), acc[2]);
        acc[3] = fmaf(a, b2f(u.w), acc[3]);
    }
    red4[lg * 64 + el] = acc;
    __syncthreads();
#pragma unroll
    for (int st = 8; st > 0; st >>= 1) {
        if (lg < st) red4[lg * 64 + el] += red4[(lg + st) * 64 + el];
        __syncthreads();
    }
    if (lg == 0)
        *(floatx4*)(ctx + b * 1024 + e) = red4[el];
}

// ---------------- softmax (fallback path) -----------------------------------
__global__ __launch_bounds__(256) void softmax_kernel(
    const float* __restrict__ part, float* __restrict__ alpha) {
    const int b = blockIdx.x;
    const int tid = threadIdx.x;
    __shared__ float red[256];
    float v[4];
    float mx = -1e30f;
#pragma unroll
    for (int i = 0; i < 4; i++) {
        const int m = b * 1024 + tid + i * 256;
        float s = 0.f;
#pragma unroll
        for (int nb = 0; nb < 16; nb++) s += part[nb * 65536 + m];
        v[i] = s;
        mx = fmaxf(mx, s);
    }
    red[tid] = mx; __syncthreads();
    for (int s = 128; s > 0; s >>= 1) {
        if (tid < s) red[tid] = fmaxf(red[tid], red[tid + s]);
        __syncthreads();
    }
    mx = red[0]; __syncthreads();
    float sum = 0.f;
#pragma unroll
    for (int i = 0; i < 4; i++) { v[i] = __expf(v[i] - mx); sum += v[i]; }
    red[tid] = sum; __syncthreads();
    for (int s = 128; s > 0; s >>= 1) {
        if (tid < s) red[tid] += red[tid + s];
        __syncthreads();
    }
    const float inv = 1.0f / red[0];
#pragma unroll
    for (int i = 0; i < 4; i++)
        alpha[b * 1024 + tid + i * 256] = v[i] * inv;
}

// ---------------- context fp32 (fallback path only) -------------------------
__global__ __launch_bounds__(1024) void context_kernel(
    const float* __restrict__ alpha, const float* __restrict__ feat,
    float* __restrict__ ctx) {
    const int b  = blockIdx.y;
    const int el = threadIdx.x & 63;
    const int lg = threadIdx.x >> 6;
    const int e  = blockIdx.x * 256 + el * 4;
    const float* fb = feat + (size_t)b * 1024 * 1024;
    const float* ab = alpha + b * 1024;
    floatx4 acc = {};
    const int l0 = lg * 64;
#pragma unroll 4
    for (int l = l0; l < l0 + 64; l++) {
        const float a = ab[l];
        const floatx4 f = *(const floatx4*)(fb + (size_t)l * 1024 + e);
        acc += a * f;
    }
    __shared__ floatx4 red[16 * 64];
    red[lg * 64 + el] = acc;
    __syncthreads();
#pragma unroll
    for (int s = 8; s > 0; s >>= 1) {
        if (lg < s) red[lg * 64 + el] += red[(lg + s) * 64 + el];
        __syncthreads();
    }
    if (lg == 0)
        *(floatx4*)(ctx + b * 1024 + e) = red[el];
}

// ---------------- fallback GEMM (fp32 A staging, padded LDS) ----------------
#define KP 72
__global__ __launch_bounds__(256) void gemm_scores_f32_kernel(
    const float* __restrict__ feat, const ushort_t* __restrict__ w1t,
    const float* __restrict__ ph, const float* __restrict__ vw,
    float* __restrict__ part) {
    __shared__ ushort_t Asf[128 * KP];
    __shared__ ushort_t Bsf[128 * KP];
    __shared__ float cbias[128];
    __shared__ float vvw[128];
    const int tid = threadIdx.x;
    const int nt = blockIdx.x, n0 = nt * 128, m0 = blockIdx.y * 128;
    const int b = m0 >> 10;
    if (tid < 128) { cbias[tid] = ph[(b << 10) + n0 + tid]; vvw[tid] = vw[n0 + tid]; }
    const int wave = tid >> 6, lane = tid & 63;
    const int wr = (wave >> 1) * 64, wc = (wave & 1) * 64;
    const int q = lane >> 4, l15 = lane & 15;
    floatx4 acc[4][4] = {};
    const int arow = tid >> 4, acol = (tid & 15) * 4;
    const int brow = tid >> 3, bcol = (tid & 7) * 8;
    const float* aptr = feat + (size_t)m0 * 1024;
    const ushort_t* bptr = w1t + (size_t)n0 * 1024;
    for (int kt = 0; kt < 1024; kt += 64) {
#pragma unroll
        for (int p = 0; p < 8; p++) {
            int r = p * 16 + arow;
            const float4 f = *(const float4*)(aptr + (size_t)r * 1024 + kt + acol);
            *(u64*)&Asf[r * KP + acol] = pack4(f);
        }
#pragma unroll
        for (int p = 0; p < 4; p++) {
            int r = p * 32 + brow;
            *(uint4*)&Bsf[r * KP + bcol] =
                *(const uint4*)(bptr + (size_t)r * 1024 + kt + bcol);
        }
        __syncthreads();
#pragma unroll
        for (int ks = 0; ks < 64; ks += 32) {
            bf16x8 af[4], bfr[4];
#pragma unroll
            for (int t = 0; t < 4; t++)
                af[t] = *(const bf16x8*)&Asf[(wr + t * 16 + l15) * KP + ks + q * 8];
#pragma unroll
            for (int t = 0; t < 4; t++)
                bfr[t] = *(const bf16x8*)&Bsf[(wc + t * 16 + l15) * KP + ks + q * 8];
#pragma unroll
            for (int tm = 0; tm < 4; tm++)
#pragma unroll
                for (int tn = 0; tn < 4; tn++)
                    acc[tm][tn] = __builtin_amdgcn_mfma_f32_16x16x32_bf16(
                        af[tm], bfr[tn], acc[tm][tn], 0, 0, 0);
        }
        __syncthreads();
    }
    const int slot = nt * 2 + (wave & 1);
#pragma unroll
    for (int tm = 0; tm < 4; tm++) {
#pragma unroll
        for (int r = 0; r < 4; r++) {
            const int row = wr + tm * 16 + q * 4 + r;
            float s = 0.f;
#pragma unroll
            for (int tn = 0; tn < 4; tn++) {
                const int col = wc + tn * 16 + l15;
                s += fast_tanh(acc[tm][tn][r] + cbias[col]) * vvw[col];
            }
            s += __shfl_xor(s, 1);
            s += __shfl_xor(s, 2);
            s += __shfl_xor(s, 4);
            s += __shfl_xor(s, 8);
            if (l15 == 0) part[slot * 65536 + m0 + row] = s;
        }
    }
}

// ---------------- launcher --------------------------------------------------
extern "C" void kernel_launch(void* const* d_in, const int* in_sizes, int n_in,
                              void* d_out, int out_size, void* d_ws, size_t ws_size,
                              hipStream_t stream) {
    const float* feat = (const float*)d_in[0];   // [64,1024,1024]
    const float* hid  = (const float*)d_in[1];   // [64,1024]
    const float* w1w  = (const float*)d_in[2];   // [1024,1024]
    const float* w1b  = (const float*)d_in[3];   // [1024]
    const float* w2w  = (const float*)d_in[4];   // [1024,1024]
    const float* w2b  = (const float*)d_in[5];   // [1024]
    const float* vw   = (const float*)d_in[6];   // [1024]
    // d_in[7] = V_b: cancels in softmax -> unused

    const size_t FEATB_BYTES = (size_t)64 * 1024 * 1024 * 2;  // 128 MB
    const size_t W1T_BYTES   = (size_t)1024 * 1024 * 2;       // 2 MB
    const size_t PH_BYTES    = (size_t)64 * 1024 * 4;         // 256 KB
    const size_t PART_BYTES  = (size_t)16 * 65536 * 4;        // 4 MB
    const bool   big_ws = ws_size >= FEATB_BYTES + W1T_BYTES + PH_BYTES + PART_BYTES;
    if (!big_ws && ws_size < W1T_BYTES + PH_BYTES + PART_BYTES) return;

    char* ws = (char*)d_ws;
    ushort_t* featb = (ushort_t*)ws;
    size_t off = big_ws ? FEATB_BYTES : 0;
    ushort_t* w1t  = (ushort_t*)(ws + off);
    float* ph      = (float*)(ws + off + W1T_BYTES);
    float* part    = (float*)(ws + off + W1T_BYTES + PH_BYTES);

    float* alpha = (float*)d_out;           // [64,1024]
    float* ctx   = alpha + 64 * 1024;       // [64,1024]

    transpose_w1_kernel<<<dim3(16, 16), 256, 0, stream>>>(w1w, w1t);
    projh_kernel<<<dim3(16, 64), 256, 0, stream>>>(hid, w2w, w2b, w1b, ph);
    if (big_ws) {
        convert_feat_kernel<<<32768, 256, 0, stream>>>(feat, featb);
        gemm_scores_256_kernel<<<dim3(1024), 512, 0, stream>>>(
            featb, w1t, ph, vw, part);
        softmax_context_kernel<<<dim3(4, 64), 1024, 0, stream>>>(
            part, featb, alpha, ctx);
    } else {
        gemm_scores_f32_kernel<<<dim3(8, 512), 256, 0, stream>>>(
            feat, w1t, ph, vw, part);
        softmax_kernel<<<64, 256, 0, stream>>>(part, alpha);
        context_kernel<<<dim3(4, 64), 1024, 0, stream>>>(alpha, feat, ctx);
    }
}

// Round 9
// 573.736 us; speedup vs baseline: 1.0183x; 1.0183x over previous
//
#include <hip/hip_runtime.h>
#include <hip/hip_bf16.h>

// Problem: B=64, L=1024, ENC=1024, DEC=1024, ATT=1024
// M = B*L = 65536, K = ENC = 1024, N = ATT = 1024
//
// Pipeline (fast path, needs ~135 MB ws), 5 dispatches:
//   ws: [featb bf16 128MB][W1T bf16 2MB][proj_h fp32 256KB][part fp32 4MB]
//   1. transpose W1 (fp32 [K][N]) -> W1T (bf16 [N][K])
//   2. proj_h = hidden@W2 + W2_b + W1_b   (combined bias)
//   3. convert features fp32 -> bf16 (featb)
//   4. GEMM proj_f = featb@W1T: 256x256 tile, BK=64, **16 waves** (4Mx4N,
//      wave tile 64x64, acc=64 regs -> 4 waves/SIMD vs prior 2), 2-barrier
//      per K-tile, counted vmcnt(4) (never 0 in loop), gload_lds +
//      swizzled LDS, tanh epilogue:
//        part[nt*4 + wn][m] = sum_{a in 64-col chunk} tanh(pf+ph)*V_w
//   5. fused softmax+context: per (e-quarter, b) block redundant softmax
//      from the 16 partials (alpha in LDS; x==0 block writes alpha), then
//      context quarter from bf16 featb.

typedef __bf16 bf16x8 __attribute__((ext_vector_type(8)));
typedef float floatx4 __attribute__((ext_vector_type(4)));
typedef unsigned short ushort_t;
typedef unsigned long long u64;

__device__ __forceinline__ ushort_t f2b(float x) {
    union { float f; unsigned u; } v; v.f = x;
    unsigned r = (v.u + 0x7fffu + ((v.u >> 16) & 1u)) >> 16;  // RNE
    return (ushort_t)r;
}

__device__ __forceinline__ float b2f(ushort_t u) {
    union { unsigned u; float f; } v; v.u = (unsigned)u << 16; return v.f;
}

__device__ __forceinline__ u64 pack4(float4 f) {
    return (u64)f2b(f.x) | ((u64)f2b(f.y) << 16) |
           ((u64)f2b(f.z) << 32) | ((u64)f2b(f.w) << 48);
}

__device__ __forceinline__ void gload_lds16(const void* g, void* l) {
    __builtin_amdgcn_global_load_lds(
        (const __attribute__((address_space(1))) void*)g,
        (__attribute__((address_space(3))) void*)l, 16, 0, 0);
}

// tanh via v_exp_f32 + v_rcp_f32 (fallback kernel only)
__device__ __forceinline__ float fast_tanh(float x) {
    const float ax = fabsf(x);
    const float t  = __expf(-2.0f * ax);
    const float r  = (1.0f - t) * __builtin_amdgcn_rcpf(1.0f + t);
    return copysignf(r, x);
}

#define LOG2E2 2.885390082f   // 2/ln(2): e^{2x} = 2^{x*LOG2E2}

// ---------------- features fp32 -> bf16 -------------------------------------
__global__ __launch_bounds__(256) void convert_feat_kernel(
    const float* __restrict__ feat, ushort_t* __restrict__ featb) {
    const size_t idx = ((size_t)blockIdx.x * 256 + threadIdx.x) * 8;
    const float4 f0 = *(const float4*)(feat + idx);
    const float4 f1 = *(const float4*)(feat + idx + 4);
    *(u64*)(featb + idx)     = pack4(f0);
    *(u64*)(featb + idx + 4) = pack4(f1);
}

// ---------------- W1 transpose + bf16 convert: [K][N] fp32 -> [N][K] bf16 ---
__global__ __launch_bounds__(256) void transpose_w1_kernel(
    const float* __restrict__ w1, ushort_t* __restrict__ w1t) {
    __shared__ ushort_t tile[64][65];
    const int k0 = blockIdx.x * 64, n0 = blockIdx.y * 64;
    const int tr = threadIdx.x >> 6;   // 0..3
    const int tc = threadIdx.x & 63;   // 0..63
#pragma unroll
    for (int i = 0; i < 16; i++) {
        int r = i * 4 + tr;
        tile[tc][r] = f2b(w1[(size_t)(k0 + r) * 1024 + n0 + tc]);
    }
    __syncthreads();
#pragma unroll
    for (int i = 0; i < 16; i++) {
        int r = i * 4 + tr;
        w1t[(size_t)(n0 + r) * 1024 + k0 + tc] = tile[r][tc];
    }
}

// ---------------- proj_h = hidden @ W2 + W2_b + W1_b ------------------------
__global__ __launch_bounds__(256) void projh_kernel(
    const float* __restrict__ hidden, const float* __restrict__ w2,
    const float* __restrict__ w2b, const float* __restrict__ w1b,
    float* __restrict__ ph) {
    const int b  = blockIdx.y;
    const int al = threadIdx.x & 63;
    const int eg = threadIdx.x >> 6;            // 0..3
    const int a  = blockIdx.x * 64 + al;
    const float* h = hidden + b * 1024;
    float sum = 0.f;
    const int e0 = eg * 256;
#pragma unroll 8
    for (int e = e0; e < e0 + 256; e++)
        sum += h[e] * w2[(size_t)e * 1024 + a];
    __shared__ float red[256];
    red[threadIdx.x] = sum;
    __syncthreads();
    if (threadIdx.x < 64)
        ph[b * 1024 + a] = w2b[a] + w1b[a] + red[al] + red[al + 64] +
                           red[al + 128] + red[al + 192];
}

// ---------------- main GEMM: 256x256 tile, 16 waves, 2-barrier/K-tile -------
// LDS per operand buffer: [2 dbuf][2 k-half][16 row-groups][1KB segment]
//   segment = 16 rows x 32 cols bf16; within a row (4 16B-blocks) block g of
//   row r is stored at slot g ^ ((r>>1)&3)  (conflict-free b128 reads,
//   SQ_LDS_BANK_CONFLICT = 0 measured on this layout).
// gload_lds dest is LINEAR (base + lane*16B); swizzle via pre-swizzled
// GLOBAL source (guide rule 21 / m173).
//
// 16 waves (1024 thr): one collective STG = 1024 lanes x 16B = one 16 KB
// (operand, k-half) sub-tile -> 1 gload_lds per wave per STG.
// vmcnt ledger (steady state, per wave; issue order oldest->youngest):
//   enter tile t: [A(t,h1), B(t,h1), A(t+1,h0), B(t+1,h0)]
//   +A(t+1,h1) +B(t+1,h1) -> 6
//   WAITV(4): drains {A,B}(t,h1)   (read by PHASE(d,1) after the barrier)
//   +A(t+2,h0) +B(t+2,h0) -> 6
//   WAITV(4): drains {A,B}(t+1,h0) (read by next tile's PHASE after barrier)
// Never vmcnt(0) in the loop. Stage-into-read-buffer hazard: writes to buf
// d's h0 (STG k2) are issued after the mid-tile barrier; all h0 ds_reads
// completed before it (compiler lgkm waits precede the pre-barrier MFMAs).
// Waves 0-3 carry 2 older bias loads: counted waits only become stricter.

#define WAITV(n) asm volatile("s_waitcnt vmcnt(" #n ")" ::: "memory")
#define BAR() __builtin_amdgcn_s_barrier()

#define STG_A(d, h, kc) \
    gload_lds16(aSrc + (kc) + (h) * 32, aDst + (d) * 16384 + (h) * 8192)
#define STG_B(d, h, kc) \
    gload_lds16(bSrc + (kc) + (h) * 32, bDst + (d) * 16384 + (h) * 8192)

#define PHASE(d, h) do { \
    bf16x8 af[4], bfr[4]; \
    _Pragma("unroll") \
    for (int i_ = 0; i_ < 4; i_++) \
      af[i_] = *(const bf16x8*)(As + (d) * 16384 + (h) * 8192 + \
                                (ga + i_) * 512 + rdo); \
    _Pragma("unroll") \
    for (int j_ = 0; j_ < 4; j_++) \
      bfr[j_] = *(const bf16x8*)(Bs + (d) * 16384 + (h) * 8192 + \
                                 (gb + j_) * 512 + rdo); \
    __builtin_amdgcn_s_setprio(1); \
    _Pragma("unroll") \
    for (int i_ = 0; i_ < 4; i_++) \
      _Pragma("unroll") \
      for (int j_ = 0; j_ < 4; j_++) \
        acc[i_][j_] = __builtin_amdgcn_mfma_f32_16x16x32_bf16( \
            af[i_], bfr[j_], acc[i_][j_], 0, 0, 0); \
    __builtin_amdgcn_s_setprio(0); \
  } while (0)

#define TILE(t, d) do { \
    const int k1_ = (((t) + 1) & 15) * 64; \
    const int k2_ = (((t) + 2) & 15) * 64; \
    STG_A(d ^ 1, 1, k1_); \
    PHASE(d, 0); \
    STG_B(d ^ 1, 1, k1_); \
    WAITV(4); BAR(); \
    STG_A(d, 0, k2_); \
    PHASE(d, 1); \
    STG_B(d, 0, k2_); \
    WAITV(4); BAR(); \
  } while (0)

__global__ __launch_bounds__(1024) void gemm_scores_256_kernel(
    const ushort_t* __restrict__ featb,  // [M][1024] bf16
    const ushort_t* __restrict__ w1t,    // [N][1024] bf16
    const float* __restrict__ ph,        // [B][1024] combined bias
    const float* __restrict__ vw,        // [1024]
    float* __restrict__ part) {          // [16][M] fp32 partial scores
    __shared__ ushort_t As[2 * 16384];   // 64 KB
    __shared__ ushort_t Bs[2 * 16384];   // 64 KB
    __shared__ float cbias[256];
    __shared__ float vvw[256];

    const int tid = threadIdx.x;
    // XCD-chunked bijective remap (1024 wgs % 8 == 0).
    const int orig = blockIdx.x;
    const int wgid = (orig & 7) * 128 + (orig >> 3);
    const int nt = wgid & 3;             // n fastest: 4 wgids share one A-tile
    const int mt = wgid >> 2;
    const int n0 = nt * 256;
    const int m0 = mt * 256;
    const int b  = m0 >> 10;             // one batch row per block (256|1024)

    if (tid < 256) {
        cbias[tid] = ph[(b << 10) + n0 + tid];
        vvw[tid]   = vw[n0 + tid];
    }

    const int w    = tid >> 6;           // wave 0..15: (w>>2)=M-quarter, (w&3)=N-quarter
    const int lane = tid & 63;
    const int q    = lane >> 4;
    const int l15  = lane & 15;
    const int rdo  = l15 * 32 + ((q ^ ((l15 >> 1) & 3)) << 3);
    const int ga   = (w >> 2) * 4;       // A row-group base (4 groups = 64 rows)
    const int gb   = (w & 3) * 4;        // B row-group base
    const int sb   = ((lane & 3) ^ ((lane >> 3) & 3)) << 3;

    const ushort_t* aSrc = featb + (size_t)(m0 + w * 16 + (lane >> 2)) * 1024 + sb;
    const ushort_t* bSrc = w1t  + (size_t)(n0 + w * 16 + (lane >> 2)) * 1024 + sb;
    ushort_t* aDst = As + w * 512;       // wave-uniform LDS base per issue
    ushort_t* bDst = Bs + w * 512;

    floatx4 acc[4][4] = {};

    // Prologue: 6 gloads = (0,h0) (0,h1) (1,h0); wait oldest 2 = (0,h0).
    STG_A(0, 0, 0);  STG_B(0, 0, 0);
    STG_A(0, 1, 0);  STG_B(0, 1, 0);
    STG_A(1, 0, 64); STG_B(1, 0, 64);
    WAITV(4); BAR();

    for (int it = 0; it < 8; it++) {
        TILE(2 * it,     0);
        TILE(2 * it + 1, 1);
    }
    WAITV(0);  // drain tail prefetches before block retires

    // Epilogue: C/D layout col=lane&15, row=q*4+reg (measured m89/m91).
    float vv[4], cbk[4];
    float sum_vvw = 0.f;
#pragma unroll
    for (int j = 0; j < 4; j++) {
        const int col = (w & 3) * 64 + j * 16 + l15;
        vv[j]  = vvw[col];
        cbk[j] = LOG2E2 * cbias[col];
        sum_vvw += vv[j];
    }
    const int slot  = nt * 4 + (w & 3);  // 16 col-chunk slots of 64
    const int rbase = m0 + (w >> 2) * 64;
#pragma unroll
    for (int mf = 0; mf < 4; mf++) {
#pragma unroll
        for (int r = 0; r < 4; r++) {
            const int row = rbase + mf * 16 + q * 4 + r;
            float s2 = 0.f;
#pragma unroll
            for (int j = 0; j < 4; j++) {
                const float arg = fmaf(LOG2E2, acc[mf][j][r], cbk[j]);
                const float e   = __builtin_amdgcn_exp2f(arg);
                s2 = fmaf(__builtin_amdgcn_rcpf(1.0f + e), vv[j], s2);
            }
            float s = fmaf(-2.0f, s2, sum_vvw);
            s += __shfl_xor(s, 1);
            s += __shfl_xor(s, 2);
            s += __shfl_xor(s, 4);
            s += __shfl_xor(s, 8);
            if (l15 == 0) part[slot * 65536 + row] = s;
        }
    }
}

// ---------------- fused softmax + context (fast path) -----------------------
// grid (4, 64), 1024 threads. Each block redundantly computes batch b's
// softmax from the 16 partials (64 KB slice, L2-resident; plain LDS trees),
// keeps alpha in LDS (block x==0 writes it out), then computes its 256-col
// context quarter from bf16 featb.
__global__ __launch_bounds__(1024) void softmax_context_kernel(
    const float* __restrict__ part, const ushort_t* __restrict__ featb,
    float* __restrict__ alpha, float* __restrict__ ctx) {
    const int b   = blockIdx.y;
    const int tid = threadIdx.x;
    __shared__ float red1[1024];
    __shared__ float al_lds[1024];
    __shared__ floatx4 red4[16 * 64];

    // score for row l = tid (same nb summation order as before)
    float s = 0.f;
    const int m = b * 1024 + tid;
#pragma unroll
    for (int nb = 0; nb < 16; nb++) s += part[nb * 65536 + m];

    // block max (LDS tree; exact)
    red1[tid] = s;
    __syncthreads();
    for (int st = 512; st > 0; st >>= 1) {
        if (tid < st) red1[tid] = fmaxf(red1[tid], red1[tid + st]);
        __syncthreads();
    }
    const float mx = red1[0];
    __syncthreads();                      // all reads of red1[0] before reuse

    const float v = __expf(s - mx);
    red1[tid] = v;
    __syncthreads();
    for (int st = 512; st > 0; st >>= 1) {
        if (tid < st) red1[tid] += red1[tid + st];
        __syncthreads();
    }
    const float av = v * (1.0f / red1[0]);
    al_lds[tid] = av;
    if (blockIdx.x == 0) alpha[m] = av;
    __syncthreads();

    // context quarter: ctx[b][e..e+3] over this block's 256 cols
    const int el = tid & 63, lg = tid >> 6;
    const int e  = blockIdx.x * 256 + el * 4;
    const ushort_t* fb = featb + ((size_t)b << 20) + e;
    floatx4 acc = {};
    const int l0 = lg * 64;
#pragma unroll 4
    for (int l = l0; l < l0 + 64; l++) {
        const float a = al_lds[l];
        const ushort4 u = *(const ushort4*)(fb + (size_t)l * 1024);
        acc[0] = fmaf(a, b2f(u.x), acc[0]);
        acc[1] = fmaf(a, b2f(u.y), acc[1]);
        acc[2] = fmaf(a, b2f(u.z), acc[2]);
        acc[3] = fmaf(a, b2f(u.w), acc[3]);
    }
    red4[lg * 64 + el] = acc;
    __syncthreads();
#pragma unroll
    for (int st = 8; st > 0; st >>= 1) {
        if (lg < st) red4[lg * 64 + el] += red4[(lg + st) * 64 + el];
        __syncthreads();
    }
    if (lg == 0)
        *(floatx4*)(ctx + b * 1024 + e) = red4[el];
}

// ---------------- softmax (fallback path) -----------------------------------
__global__ __launch_bounds__(256) void softmax_kernel(
    const float* __restrict__ part, float* __restrict__ alpha) {
    const int b = blockIdx.x;
    const int tid = threadIdx.x;
    __shared__ float red[256];
    float v[4];
    float mx = -1e30f;
#pragma unroll
    for (int i = 0; i < 4; i++) {
        const int m = b * 1024 + tid + i * 256;
        float s = 0.f;
#pragma unroll
        for (int nb = 0; nb < 16; nb++) s += part[nb * 65536 + m];
        v[i] = s;
        mx = fmaxf(mx, s);
    }
    red[tid] = mx; __syncthreads();
    for (int s = 128; s > 0; s >>= 1) {
        if (tid < s) red[tid] = fmaxf(red[tid], red[tid + s]);
        __syncthreads();
    }
    mx = red[0]; __syncthreads();
    float sum = 0.f;
#pragma unroll
    for (int i = 0; i < 4; i++) { v[i] = __expf(v[i] - mx); sum += v[i]; }
    red[tid] = sum; __syncthreads();
    for (int s = 128; s > 0; s >>= 1) {
        if (tid < s) red[tid] += red[tid + s];
        __syncthreads();
    }
    const float inv = 1.0f / red[0];
#pragma unroll
    for (int i = 0; i < 4; i++)
        alpha[b * 1024 + tid + i * 256] = v[i] * inv;
}

// ---------------- context fp32 (fallback path only) -------------------------
__global__ __launch_bounds__(1024) void context_kernel(
    const float* __restrict__ alpha, const float* __restrict__ feat,
    float* __restrict__ ctx) {
    const int b  = blockIdx.y;
    const int el = threadIdx.x & 63;
    const int lg = threadIdx.x >> 6;
    const int e  = blockIdx.x * 256 + el * 4;
    const float* fb = feat + (size_t)b * 1024 * 1024;
    const float* ab = alpha + b * 1024;
    floatx4 acc = {};
    const int l0 = lg * 64;
#pragma unroll 4
    for (int l = l0; l < l0 + 64; l++) {
        const float a = ab[l];
        const floatx4 f = *(const floatx4*)(fb + (size_t)l * 1024 + e);
        acc += a * f;
    }
    __shared__ floatx4 red[16 * 64];
    red[lg * 64 + el] = acc;
    __syncthreads();
#pragma unroll
    for (int s = 8; s > 0; s >>= 1) {
        if (lg < s) red[lg * 64 + el] += red[(lg + s) * 64 + el];
        __syncthreads();
    }
    if (lg == 0)
        *(floatx4*)(ctx + b * 1024 + e) = red[el];
}

// ---------------- fallback GEMM (fp32 A staging, padded LDS) ----------------
#define KP 72
__global__ __launch_bounds__(256) void gemm_scores_f32_kernel(
    const float* __restrict__ feat, const ushort_t* __restrict__ w1t,
    const float* __restrict__ ph, const float* __restrict__ vw,
    float* __restrict__ part) {
    __shared__ ushort_t Asf[128 * KP];
    __shared__ ushort_t Bsf[128 * KP];
    __shared__ float cbias[128];
    __shared__ float vvw[128];
    const int tid = threadIdx.x;
    const int nt = blockIdx.x, n0 = nt * 128, m0 = blockIdx.y * 128;
    const int b = m0 >> 10;
    if (tid < 128) { cbias[tid] = ph[(b << 10) + n0 + tid]; vvw[tid] = vw[n0 + tid]; }
    const int wave = tid >> 6, lane = tid & 63;
    const int wr = (wave >> 1) * 64, wc = (wave & 1) * 64;
    const int q = lane >> 4, l15 = lane & 15;
    floatx4 acc[4][4] = {};
    const int arow = tid >> 4, acol = (tid & 15) * 4;
    const int brow = tid >> 3, bcol = (tid & 7) * 8;
    const float* aptr = feat + (size_t)m0 * 1024;
    const ushort_t* bptr = w1t + (size_t)n0 * 1024;
    for (int kt = 0; kt < 1024; kt += 64) {
#pragma unroll
        for (int p = 0; p < 8; p++) {
            int r = p * 16 + arow;
            const float4 f = *(const float4*)(aptr + (size_t)r * 1024 + kt + acol);
            *(u64*)&Asf[r * KP + acol] = pack4(f);
        }
#pragma unroll
        for (int p = 0; p < 4; p++) {
            int r = p * 32 + brow;
            *(uint4*)&Bsf[r * KP + bcol] =
                *(const uint4*)(bptr + (size_t)r * 1024 + kt + bcol);
        }
        __syncthreads();
#pragma unroll
        for (int ks = 0; ks < 64; ks += 32) {
            bf16x8 af[4], bfr[4];
#pragma unroll
            for (int t = 0; t < 4; t++)
                af[t] = *(const bf16x8*)&Asf[(wr + t * 16 + l15) * KP + ks + q * 8];
#pragma unroll
            for (int t = 0; t < 4; t++)
                bfr[t] = *(const bf16x8*)&Bsf[(wc + t * 16 + l15) * KP + ks + q * 8];
#pragma unroll
            for (int tm = 0; tm < 4; tm++)
#pragma unroll
                for (int tn = 0; tn < 4; tn++)
                    acc[tm][tn] = __builtin_amdgcn_mfma_f32_16x16x32_bf16(
                        af[tm], bfr[tn], acc[tm][tn], 0, 0, 0);
        }
        __syncthreads();
    }
    const int slot = nt * 2 + (wave & 1);
#pragma unroll
    for (int tm = 0; tm < 4; tm++) {
#pragma unroll
        for (int r = 0; r < 4; r++) {
            const int row = wr + tm * 16 + q * 4 + r;
            float s = 0.f;
#pragma unroll
            for (int tn = 0; tn < 4; tn++) {
                const int col = wc + tn * 16 + l15;
                s += fast_tanh(acc[tm][tn][r] + cbias[col]) * vvw[col];
            }
            s += __shfl_xor(s, 1);
            s += __shfl_xor(s, 2);
            s += __shfl_xor(s, 4);
            s += __shfl_xor(s, 8);
            if (l15 == 0) part[slot * 65536 + m0 + row] = s;
        }
    }
}

// ---------------- launcher --------------------------------------------------
extern "C" void kernel_launch(void* const* d_in, const int* in_sizes, int n_in,
                              void* d_out, int out_size, void* d_ws, size_t ws_size,
                              hipStream_t stream) {
    const float* feat = (const float*)d_in[0];   // [64,1024,1024]
    const float* hid  = (const float*)d_in[1];   // [64,1024]
    const float* w1w  = (const float*)d_in[2];   // [1024,1024]
    const float* w1b  = (const float*)d_in[3];   // [1024]
    const float* w2w  = (const float*)d_in[4];   // [1024,1024]
    const float* w2b  = (const float*)d_in[5];   // [1024]
    const float* vw   = (const float*)d_in[6];   // [1024]
    // d_in[7] = V_b: cancels in softmax -> unused

    const size_t FEATB_BYTES = (size_t)64 * 1024 * 1024 * 2;  // 128 MB
    const size_t W1T_BYTES   = (size_t)1024 * 1024 * 2;       // 2 MB
    const size_t PH_BYTES    = (size_t)64 * 1024 * 4;         // 256 KB
    const size_t PART_BYTES  = (size_t)16 * 65536 * 4;        // 4 MB
    const bool   big_ws = ws_size >= FEATB_BYTES + W1T_BYTES + PH_BYTES + PART_BYTES;
    if (!big_ws && ws_size < W1T_BYTES + PH_BYTES + PART_BYTES) return;

    char* ws = (char*)d_ws;
    ushort_t* featb = (ushort_t*)ws;
    size_t off = big_ws ? FEATB_BYTES : 0;
    ushort_t* w1t  = (ushort_t*)(ws + off);
    float* ph      = (float*)(ws + off + W1T_BYTES);
    float* part    = (float*)(ws + off + W1T_BYTES + PH_BYTES);

    float* alpha = (float*)d_out;           // [64,1024]
    float* ctx   = alpha + 64 * 1024;       // [64,1024]

    transpose_w1_kernel<<<dim3(16, 16), 256, 0, stream>>>(w1w, w1t);
    projh_kernel<<<dim3(16, 64), 256, 0, stream>>>(hid, w2w, w2b, w1b, ph);
    if (big_ws) {
        convert_feat_kernel<<<32768, 256, 0, stream>>>(feat, featb);
        gemm_scores_256_kernel<<<dim3(1024), 1024, 0, stream>>>(
            featb, w1t, ph, vw, part);
        softmax_context_kernel<<<dim3(4, 64), 1024, 0, stream>>>(
            part, featb, alpha, ctx);
    } else {
        gemm_scores_f32_kernel<<<dim3(8, 512), 256, 0, stream>>>(
            feat, w1t, ph, vw, part);
        softmax_kernel<<<64, 256, 0, stream>>>(part, alpha);
        context_kernel<<<dim3(4, 64), 1024, 0, stream>>>(alpha, feat, ctx);
    }
}